// Round 8
// baseline (249.961 us; speedup 1.0000x reference)
//
#include <hip/hip_runtime.h>
#include <hip/hip_bf16.h>
#include <math.h>

// Problem constants: B=8192, E=16, H=1024
#define B_SZ 8192
#define H_SZ 1024
#define E_SZ 16
#define NT   64          // 8192/128 panels
#define SIM_THR 0.8f

typedef float floatx4 __attribute__((ext_vector_type(4)));
typedef int   intx4   __attribute__((ext_vector_type(4)));
typedef int   intx8   __attribute__((ext_vector_type(8)));

// ---------------- workspace layout ----------------
// 0: float gsum | 4: uint gcnt | 8: uint done
#define OFF_NE   4096
#define OFF_L    65536
#define OFF_P    (65536 + 524288)
#define OFF_EMB  2097152   // fp8 emb, MX-MFMA-native layout: 8 MB

// MX-MFMA-native fp8 layout (for mfma_scale_f32_16x16x128_f8f6f4):
// lane (q=lane>>4, m=lane&15) needs rows m, k in [q*32, q*32+32) contiguous.
// addr(r,k) = (r>>4)*16384 + (k>>7)*2048 + ((k>>4)&1)*1024 + ((k>>5)&3)*256
//           + (r&15)*16 + (k&15)
// => fragment = two b128 reads at  group*2048 + lane*16  and  +1024
//    (group = (r>>4), per K-window of 128; regs k-sequential).

__device__ __forceinline__ void gload16(const void* g, void* l) {
    __builtin_amdgcn_global_load_lds(
        (const __attribute__((address_space(1))) void*)g,
        (__attribute__((address_space(3))) void*)l, 16, 0, 0);
}

// ---------------------------------------------------------------------------
// Prep: blocks 0..511 normalize 16 rows each -> fp8 MX layout with LDS-staged
// fully-coalesced 16-KB group writes; blocks 512..543 softmax tables + init.
// ---------------------------------------------------------------------------
__global__ __launch_bounds__(256)
void prep_kernel(const float* __restrict__ rp,
                 const float* __restrict__ emb,
                 unsigned char* __restrict__ out8,
                 float* __restrict__ L, float* __restrict__ P,
                 float* __restrict__ ne,
                 float* __restrict__ gsum, unsigned int* __restrict__ gcnt,
                 unsigned int* __restrict__ done) {
    const int b = blockIdx.x;
    const int tid = threadIdx.x;
    if (b < 512) {
        __shared__ __align__(16) unsigned char stage[16 * 1040]; // padded rows
        const int wave = tid >> 6, lane = tid & 63;
        const int g = b;
#pragma unroll
        for (int t = 0; t < 4; t++) {
            int r = g * 16 + wave * 4 + t;
            const float4* row4 = (const float4*)(emb + (size_t)r * H_SZ);
            float4 v0 = row4[lane * 4 + 0], v1 = row4[lane * 4 + 1];
            float4 v2 = row4[lane * 4 + 2], v3 = row4[lane * 4 + 3];
            float ss = v0.x*v0.x + v0.y*v0.y + v0.z*v0.z + v0.w*v0.w
                     + v1.x*v1.x + v1.y*v1.y + v1.z*v1.z + v1.w*v1.w
                     + v2.x*v2.x + v2.y*v2.y + v2.z*v2.z + v2.w*v2.w
                     + v3.x*v3.x + v3.y*v3.y + v3.z*v3.z + v3.w*v3.w;
#pragma unroll
            for (int off = 32; off > 0; off >>= 1) ss += __shfl_down(ss, off, 64);
            ss = __shfl(ss, 0, 64);
            float inv = rsqrtf(ss);
            unsigned int w0, w1, w2, w3;
            w0 = (unsigned int)__builtin_amdgcn_cvt_pk_fp8_f32(v0.x*inv, v0.y*inv, 0, false);
            w0 = (unsigned int)__builtin_amdgcn_cvt_pk_fp8_f32(v0.z*inv, v0.w*inv, w0, true);
            w1 = (unsigned int)__builtin_amdgcn_cvt_pk_fp8_f32(v1.x*inv, v1.y*inv, 0, false);
            w1 = (unsigned int)__builtin_amdgcn_cvt_pk_fp8_f32(v1.z*inv, v1.w*inv, w1, true);
            w2 = (unsigned int)__builtin_amdgcn_cvt_pk_fp8_f32(v2.x*inv, v2.y*inv, 0, false);
            w2 = (unsigned int)__builtin_amdgcn_cvt_pk_fp8_f32(v2.z*inv, v2.w*inv, w2, true);
            w3 = (unsigned int)__builtin_amdgcn_cvt_pk_fp8_f32(v3.x*inv, v3.y*inv, 0, false);
            w3 = (unsigned int)__builtin_amdgcn_cvt_pk_fp8_f32(v3.z*inv, v3.w*inv, w3, true);
            uint4 c = {w0, w1, w2, w3};
            // row-linear staging: row m stores its 64 chunks at lane*16
            *(uint4*)(stage + (r & 15) * 1040 + lane * 16) = c;
        }
        __syncthreads();
        // coalesced write-out: chunk d maps to dst offset d*16; source chunk
        // index c = w*8 + q*2 + h within the row.
#pragma unroll
        for (int p = 0; p < 4; p++) {
            int d = p * 256 + tid;
            int w = d >> 7, h = (d >> 6) & 1, q = (d >> 4) & 3, m = d & 15;
            int c = w * 8 + q * 2 + h;
            uint4 v = *(const uint4*)(stage + m * 1040 + c * 16);
            *(uint4*)(out8 + (size_t)g * 16384 + (size_t)d * 16) = v;
        }
    } else {
        int i = (b - 512) * 256 + tid;
        if (i == 0) { *gsum = 0.f; *gcnt = 0u; *done = 0u; }
        if (i >= B_SZ) return;
        const float* x = rp + i * E_SZ;
        float v[E_SZ];
        float m = -INFINITY;
#pragma unroll
        for (int k = 0; k < E_SZ; k++) { v[k] = x[k]; m = fmaxf(m, v[k]); }
        float s = 0.f;
#pragma unroll
        for (int k = 0; k < E_SZ; k++) s += expf(v[k] - m);
        float lse = m + logf(s);
        float nent = 0.f;
#pragma unroll
        for (int k = 0; k < E_SZ; k++) {
            float l = v[k] - lse;
            float p = expf(l);
            L[i * E_SZ + k] = l;
            P[i * E_SZ + k] = p;
            nent += p * l;
        }
        ne[i] = nent;
    }
}

// count of n in [lo,hi] with n&7==r; *first = smallest such n
__device__ __forceinline__ int cnt_range(int lo, int hi, int r, int* first) {
    int lo2 = lo + ((r - lo) & 7);
    *first = lo2;
    return (lo2 > hi) ? 0 : ((hi - lo2) >> 3) + 1;
}

// ---------------------------------------------------------------------------
// Main: 128x128 sim tiles via MX-scaled fp8 MFMA (K=128, scale=1.0 -> bit-
// identical products to plain e4m3). 8 K-rounds/tile, LDS double-buffer, one
// barrier per round, 2 blocks/CU. Owner-computes XCD partition; per-wave
// compaction epilogue + fused finalize.
// ---------------------------------------------------------------------------
__global__ __launch_bounds__(256)
void sim_kl_kernel(const unsigned char* __restrict__ embL,
                   const float* __restrict__ Lm, const float* __restrict__ Pm,
                   const float* __restrict__ ne,
                   float* __restrict__ gsum, unsigned int* __restrict__ gcnt,
                   unsigned int* __restrict__ done, float* __restrict__ out) {
    __shared__ __align__(16) char As[2][16384];  // 8 groups x 2 KB per buffer
    __shared__ __align__(16) char Bs[2][16384];
    __shared__ float redf[4];
    __shared__ unsigned int redc[4];

    // --- blockIdx -> (bi, bj): XCD x owns bj panels with class(bj)==x ---
    const int x = blockIdx.x & 7;
    int s = blockIdx.x >> 3;            // 0..259
    int bi = 0, bj = 0;
    for (bi = 0; bi < NT; bi++) {
        int f1, f2;
        int n1 = (bi <= 31) ? cnt_range(bi, 31, x, &f1) : 0;
        int n2 = cnt_range(bi < 32 ? 32 : bi, 63, 7 - x, &f2);
        if (s < n1) { bj = f1 + 8 * s; break; }
        s -= n1;
        if (s < n2) { bj = f2 + 8 * s; break; }
        s -= n2;
    }
    const bool diag = (bi == bj);
    const int rowI = bi * 128, rowJ = bj * 128;

    const int tid  = threadIdx.x;
    const int lane = tid & 63;
    const int wave = tid >> 6;
    const int wr = (wave >> 1) * 64;    // wave quadrant row
    const int wc = (wave & 1) * 64;     // wave quadrant col
    const int quad = lane >> 4;
    const int l16  = lane & 15;

    floatx4 acc[4][4];
#pragma unroll
    for (int mi = 0; mi < 4; mi++)
#pragma unroll
        for (int ni = 0; ni < 4; ni++) {
            floatx4 z = {0.f, 0.f, 0.f, 0.f};
            acc[mi][ni] = z;
        }

    // staging: wave w stages groups {2w, 2w+1} of A and B (2 KB each)
    const char* srcA = (const char*)embL + (size_t)(bi * 8 + 2 * wave) * 16384 + lane * 16;
    const char* srcB = (const char*)embL + (size_t)(bj * 8 + 2 * wave) * 16384 + lane * 16;
    const int aW = 2 * wave * 2048;     // wave-uniform LDS offset

    {   // prologue: stage K-round 0 into buffer 0
        gload16(srcA,          As[0] + aW);
        gload16(srcA + 1024,   As[0] + aW + 1024);
        gload16(srcA + 16384,  As[0] + aW + 2048);
        gload16(srcA + 17408,  As[0] + aW + 3072);
        gload16(srcB,          Bs[0] + aW);
        gload16(srcB + 1024,   Bs[0] + aW + 1024);
        gload16(srcB + 16384,  Bs[0] + aW + 2048);
        gload16(srcB + 17408,  Bs[0] + aW + 3072);
    }

    const int abase = (wr >> 4) * 2048 + lane * 16;   // + mi*2048
    const int bbase = (wc >> 4) * 2048 + lane * 16;   // + ni*2048

    for (int kt = 0; kt < 8; kt++) {
        const int b = kt & 1;
        __syncthreads();                 // vmcnt drain + barrier: buffer b ready
        if (kt + 1 < 8) {                // prefetch kt+1; overlaps MFMAs below
            const int ko = (kt + 1) * 2048;
            gload16(srcA + ko,          As[b ^ 1] + aW);
            gload16(srcA + ko + 1024,   As[b ^ 1] + aW + 1024);
            gload16(srcA + ko + 16384,  As[b ^ 1] + aW + 2048);
            gload16(srcA + ko + 17408,  As[b ^ 1] + aW + 3072);
            gload16(srcB + ko,          Bs[b ^ 1] + aW);
            gload16(srcB + ko + 1024,   Bs[b ^ 1] + aW + 1024);
            gload16(srcB + ko + 16384,  Bs[b ^ 1] + aW + 2048);
            gload16(srcB + ko + 17408,  Bs[b ^ 1] + aW + 3072);
        }

        intx8 af[4], bf[4];
#pragma unroll
        for (int mi = 0; mi < 4; mi++) {
            intx4 lo = *(const intx4*)(As[b] + abase + mi * 2048);
            intx4 hi = *(const intx4*)(As[b] + abase + mi * 2048 + 1024);
            af[mi] = __builtin_shufflevector(lo, hi, 0, 1, 2, 3, 4, 5, 6, 7);
        }
#pragma unroll
        for (int ni = 0; ni < 4; ni++) {
            intx4 lo = *(const intx4*)(Bs[b] + bbase + ni * 2048);
            intx4 hi = *(const intx4*)(Bs[b] + bbase + ni * 2048 + 1024);
            bf[ni] = __builtin_shufflevector(lo, hi, 0, 1, 2, 3, 4, 5, 6, 7);
        }
#pragma unroll
        for (int mi = 0; mi < 4; mi++)
#pragma unroll
            for (int ni = 0; ni < 4; ni++)
                acc[mi][ni] = __builtin_amdgcn_mfma_scale_f32_16x16x128_f8f6f4(
                    af[mi], bf[ni], acc[mi][ni],
                    0, 0,            // cbsz=fp8(e4m3), blgp=fp8(e4m3)
                    0, 127,          // scale_a opsel, e8m0 1.0
                    0, 127);         // scale_b opsel, e8m0 1.0
    }

    // =================== per-wave compaction epilogue =======================
    __syncthreads();                 // tile reads done: overlay list on As
    unsigned short* wl = (unsigned short*)As + wave * 2048;
    int base = 0;
    // C/D layout (16x16 shape, fmt-independent): col = lane&15, row = quad*4+reg
#pragma unroll
    for (int mi = 0; mi < 4; mi++) {
#pragma unroll
        for (int ni = 0; ni < 4; ni++) {
#pragma unroll
            for (int r = 0; r < 4; r++) {
                int il = wr + mi * 16 + quad * 4 + r;
                int jl = wc + ni * 16 + l16;
                bool msk = (acc[mi][ni][r] > SIM_THR) && (rowI + il != rowJ + jl);
                unsigned long long bal = __ballot(msk);
                if (msk) {
                    int pos = base + __popcll(bal & ((1ull << lane) - 1ull));
                    if (pos < 2048) wl[pos] = (unsigned short)((il << 8) | jl);
                }
                base += __popcll(bal);
            }
        }
    }
    if (base > 2048) base = 2048;   // safety clamp (expected ~32/wave)

    float fsum = 0.f;
    unsigned int lcnt = 0;
    for (int t = lane; t < base; t += 64) {
        int e = wl[t];
        int i = rowI + (e >> 8), j = rowJ + (e & 255);
        const float4* Li4 = (const float4*)(Lm + i * E_SZ);
        const float4* Pj4 = (const float4*)(Pm + j * E_SZ);
        float d = 0.f;
#pragma unroll
        for (int q = 0; q < 4; q++) {
            float4 a = Li4[q], bb = Pj4[q];
            d += a.x * bb.x + a.y * bb.y + a.z * bb.z + a.w * bb.w;
        }
        float sv = ne[j] - d;
        unsigned int c = 1;
        if (!diag) {
            const float4* Lj4 = (const float4*)(Lm + j * E_SZ);
            const float4* Pi4 = (const float4*)(Pm + i * E_SZ);
            float d2 = 0.f;
#pragma unroll
            for (int q = 0; q < 4; q++) {
                float4 a = Lj4[q], bb = Pi4[q];
                d2 += a.x * bb.x + a.y * bb.y + a.z * bb.z + a.w * bb.w;
            }
            sv += ne[i] - d2;
            c = 2;
        }
        fsum += sv;
        lcnt += c;
    }

#pragma unroll
    for (int off = 32; off > 0; off >>= 1) {
        fsum += __shfl_down(fsum, off, 64);
        lcnt += __shfl_down(lcnt, off, 64);
    }
    if (lane == 0) { redf[wave] = fsum; redc[wave] = lcnt; }
    __syncthreads();
    if (tid == 0) {
        float sv = redf[0] + redf[1] + redf[2] + redf[3];
        unsigned int c = redc[0] + redc[1] + redc[2] + redc[3];
        if (c > 0u) {
            atomicAdd(gsum, sv);
            atomicAdd(gcnt, c);
        }
        __threadfence();                       // make accumulators visible
        unsigned int old = atomicAdd(done, 1u);
        if (old == gridDim.x - 1) {            // last block finalizes
            float S = atomicAdd(gsum, 0.0f);   // device-scope atomic read
            unsigned int C = atomicAdd(gcnt, 0u);
            out[0] = (C > 0u) ? (S / (float)C) : 0.f;   // WEIGHT = 1.0
        }
    }
}

// ---------------------------------------------------------------------------
extern "C" void kernel_launch(void* const* d_in, const int* in_sizes, int n_in,
                              void* d_out, int out_size, void* d_ws, size_t ws_size,
                              hipStream_t stream) {
    const float* rp  = (const float*)d_in[0];
    const float* emb = (const float*)d_in[1];
    float* out = (float*)d_out;

    char* ws = (char*)d_ws;
    float*         gsum = (float*)(ws + 0);
    unsigned int*  gcnt = (unsigned int*)(ws + 4);
    unsigned int*  done = (unsigned int*)(ws + 8);
    float*         ne   = (float*)(ws + OFF_NE);
    float*         Lm   = (float*)(ws + OFF_L);
    float*         Pm   = (float*)(ws + OFF_P);
    unsigned char* embL = (unsigned char*)(ws + OFF_EMB);

    prep_kernel<<<512 + 32, 256, 0, stream>>>(rp, emb, embL, Lm, Pm, ne, gsum, gcnt, done);
    const int ntri = NT * (NT + 1) / 2;  // 2080 tiles = 8 XCDs x 260
    sim_kl_kernel<<<ntri, 256, 0, stream>>>(embL, Lm, Pm, ne, gsum, gcnt, done, out);
}

// Round 9
// 165.602 us; speedup vs baseline: 1.5094x; 1.5094x over previous
//
#include <hip/hip_runtime.h>
#include <hip/hip_bf16.h>
#include <math.h>

// Problem constants: B=8192, E=16, H=1024
#define B_SZ 8192
#define H_SZ 1024
#define E_SZ 16
#define SIM_THR_I 12903   // 0.8 * 127 * 127 = 12903.2 -> D > 12903
typedef float floatx4 __attribute__((ext_vector_type(4)));
typedef int   intx4   __attribute__((ext_vector_type(4)));

// ---------------- workspace layout ----------------
// 0: float gsum | 4: uint gcnt | 8: uint done
#define OFF_NE   4096
#define OFF_L    65536
#define OFF_P    (65536 + 524288)
#define OFF_EMB  2097152   // i8 emb, MFMA-native layout: 8 MB

// MFMA-native i8 layout (for mfma_i32_16x16x64_i8, lane q*16+m holds rows m,
// k in [q*16, q*16+16) contiguous):
// addr(r,k) = (r>>4)*16384 + (k>>6)*1024 + ((k>>4)&3)*256 + (r&15)*16 + (k&15)
// => one b128 read per fragment at group*1024(round) + lane*16.

__device__ __forceinline__ void gload16(const void* g, void* l) {
    __builtin_amdgcn_global_load_lds(
        (const __attribute__((address_space(1))) void*)g,
        (__attribute__((address_space(3))) void*)l, 16, 0, 0);
}

__device__ __forceinline__ unsigned int pack4_i8(float4 v, float s) {
    int a = (int)rintf(v.x * s), b = (int)rintf(v.y * s);
    int c = (int)rintf(v.z * s), d = (int)rintf(v.w * s);
    return (a & 255) | ((b & 255) << 8) | ((c & 255) << 16) | ((d & 255) << 24);
}

// ---------------------------------------------------------------------------
// Prep: blocks 0..511 normalize 16 rows each -> i8 MFMA-native layout with
// LDS-staged coalesced writes; blocks 512..543 softmax tables + accum init.
// ---------------------------------------------------------------------------
__global__ __launch_bounds__(256)
void prep_kernel(const float* __restrict__ rp,
                 const float* __restrict__ emb,
                 unsigned char* __restrict__ out8,
                 float* __restrict__ L, float* __restrict__ P,
                 float* __restrict__ ne,
                 float* __restrict__ gsum, unsigned int* __restrict__ gcnt,
                 unsigned int* __restrict__ done) {
    const int b = blockIdx.x;
    const int tid = threadIdx.x;
    if (b < 512) {
        __shared__ __align__(16) unsigned char stage[16 * 1040]; // padded rows
        const int wave = tid >> 6, lane = tid & 63;
        const int g = b;
#pragma unroll
        for (int t = 0; t < 4; t++) {
            int r = g * 16 + wave * 4 + t;
            const float4* row4 = (const float4*)(emb + (size_t)r * H_SZ);
            // lane owns floats k in [16*lane, 16*lane+16): one 16-B i8 chunk
            float4 v0 = row4[lane * 4 + 0], v1 = row4[lane * 4 + 1];
            float4 v2 = row4[lane * 4 + 2], v3 = row4[lane * 4 + 3];
            float ss = v0.x*v0.x + v0.y*v0.y + v0.z*v0.z + v0.w*v0.w
                     + v1.x*v1.x + v1.y*v1.y + v1.z*v1.z + v1.w*v1.w
                     + v2.x*v2.x + v2.y*v2.y + v2.z*v2.z + v2.w*v2.w
                     + v3.x*v3.x + v3.y*v3.y + v3.z*v3.z + v3.w*v3.w;
#pragma unroll
            for (int off = 32; off > 0; off >>= 1) ss += __shfl_down(ss, off, 64);
            ss = __shfl(ss, 0, 64);
            float s = rsqrtf(ss) * 127.0f;
            uint4 c;
            c.x = pack4_i8(v0, s);
            c.y = pack4_i8(v1, s);
            c.z = pack4_i8(v2, s);
            c.w = pack4_i8(v3, s);
            *(uint4*)(stage + (r & 15) * 1040 + lane * 16) = c;
        }
        __syncthreads();
        // coalesced write-out: dst chunk d -> row m = d&15, src chunk
        // c = (d>>6)*4 + ((d>>4)&3)   (since d = (c>>2)*64 + (c&3)*16 + m)
#pragma unroll
        for (int p = 0; p < 4; p++) {
            int d = p * 256 + tid;
            int m = d & 15;
            int c = (d >> 6) * 4 + ((d >> 4) & 3);
            uint4 v = *(const uint4*)(stage + m * 1040 + c * 16);
            *(uint4*)(out8 + (size_t)g * 16384 + (size_t)d * 16) = v;
        }
    } else {
        int i = (b - 512) * 256 + tid;
        if (i == 0) { *gsum = 0.f; *gcnt = 0u; *done = 0u; }
        if (i >= B_SZ) return;
        const float* x = rp + i * E_SZ;
        float v[E_SZ];
        float m = -INFINITY;
#pragma unroll
        for (int k = 0; k < E_SZ; k++) { v[k] = x[k]; m = fmaxf(m, v[k]); }
        float s = 0.f;
#pragma unroll
        for (int k = 0; k < E_SZ; k++) s += expf(v[k] - m);
        float lse = m + logf(s);
        float nent = 0.f;
#pragma unroll
        for (int k = 0; k < E_SZ; k++) {
            float l = v[k] - lse;
            float p = expf(l);
            L[i * E_SZ + k] = l;
            P[i * E_SZ + k] = p;
            nent += p * l;
        }
        ne[i] = nent;
    }
}

// count of n in [lo,hi] with n&7==r; *first = smallest such n
__device__ __forceinline__ int cnt_range(int lo, int hi, int r, int* first) {
    int lo2 = lo + ((r - lo) & 7);
    *first = lo2;
    return (lo2 > hi) ? 0 : ((hi - lo2) >> 3) + 1;
}

// ---------------------------------------------------------------------------
// Main: 256x128 i8 MFMA sim tiles (512 threads, 8 waves), K=64 per MFMA ->
// 16 MFMA/round/wave (half of R7's fp8) at 2x rate. R7 staging structure:
// 3 gload16/wave/round, LDS double-buffer, one barrier per round.
// Strict j>i pair rule; owner-computes XCD partition; per-wave compaction;
// fused finalize via device-scope done counter.
// ---------------------------------------------------------------------------
#define GRID_PER_XCD 164
__global__ __launch_bounds__(512, 4)
void sim_kl_kernel(const unsigned char* __restrict__ embL,
                   const float* __restrict__ Lm, const float* __restrict__ Pm,
                   const float* __restrict__ ne,
                   float* __restrict__ gsum, unsigned int* __restrict__ gcnt,
                   unsigned int* __restrict__ done, float* __restrict__ out) {
    __shared__ __align__(16) char As[2][16384];  // 16 groups x 1 KB per buffer
    __shared__ __align__(16) char Bs[2][8192];   //  8 groups x 1 KB per buffer
    __shared__ float redf[8];
    __shared__ unsigned int redc[8];

    // --- blockIdx -> (BI, bj): XCD x owns bj panels with class(bj)==x ---
    const int x = blockIdx.x & 7;
    int s = blockIdx.x >> 3;            // slot within this XCD's tile list
    int BI = 0, bj = 0;
    bool have = false;
    for (BI = 0; BI < 32; BI++) {
        int lo = 2 * BI, f1, f2;
        int n1 = (lo <= 31) ? cnt_range(lo, 31, x, &f1) : 0;
        int n2 = cnt_range(lo < 32 ? 32 : lo, 63, 7 - x, &f2);
        if (s < n1) { bj = f1 + 8 * s; have = true; break; }
        s -= n1;
        if (s < n2) { bj = f2 + 8 * s; have = true; break; }
        s -= n2;
    }

    const int tid  = threadIdx.x;
    const int lane = tid & 63;
    const int wave = tid >> 6;

    float fsum = 0.f;
    unsigned int lcnt = 0;

    if (have) {
        const int rowI = BI * 256, rowJ = bj * 128;
        const int wrg = (wave >> 1);        // A row-group quadrant 0..3 (x64 rows)
        const int wcg = (wave & 1);         // B col-group 0..1 (x64 cols)
        const int quad = lane >> 4;
        const int l16  = lane & 15;

        intx4 acc[4][4];
#pragma unroll
        for (int mi = 0; mi < 4; mi++)
#pragma unroll
            for (int ni = 0; ni < 4; ni++) {
                intx4 z = {0, 0, 0, 0};
                acc[mi][ni] = z;
            }

        // staging: wave stages A groups {2w,2w+1} and B group {w} (1 KB each)
        const char* srcA = (const char*)embL + (size_t)(BI * 16 + 2 * wave) * 16384 + lane * 16;
        const char* srcB = (const char*)embL + (size_t)(bj * 8 + wave) * 16384 + lane * 16;
        const int aW = 2 * wave * 1024;     // wave-uniform LDS offsets
        const int bW = wave * 1024;

        {   // prologue: stage kt=0 into buffer 0
            gload16(srcA,         As[0] + aW);
            gload16(srcA + 16384, As[0] + aW + 1024);
            gload16(srcB,         Bs[0] + bW);
        }

        const int aoff = wrg * 4096 + lane * 16;   // + mi*1024
        const int boff = wcg * 4096 + lane * 16;   // + ni*1024

        for (int kt = 0; kt < 16; kt++) {
            const int b = kt & 1;
            __syncthreads();                 // vmcnt drain + barrier: buffer b ready
            if (kt + 1 < 16) {               // prefetch kt+1; overlaps MFMAs below
                const int ko = (kt + 1) * 1024;
                gload16(srcA + ko,         As[b ^ 1] + aW);
                gload16(srcA + ko + 16384, As[b ^ 1] + aW + 1024);
                gload16(srcB + ko,         Bs[b ^ 1] + bW);
            }

            intx4 af[4], bf[4];
#pragma unroll
            for (int mi = 0; mi < 4; mi++)
                af[mi] = *(const intx4*)(As[b] + aoff + mi * 1024);
#pragma unroll
            for (int ni = 0; ni < 4; ni++)
                bf[ni] = *(const intx4*)(Bs[b] + boff + ni * 1024);
#pragma unroll
            for (int mi = 0; mi < 4; mi++)
#pragma unroll
                for (int ni = 0; ni < 4; ni++)
                    acc[mi][ni] = __builtin_amdgcn_mfma_i32_16x16x64_i8(
                        af[mi], bf[ni], acc[mi][ni], 0, 0, 0);
        }

        // ============== per-wave compaction epilogue (strict j>i) ===========
        __syncthreads();             // tile reads done: overlay list on As
        unsigned short* wl = (unsigned short*)As + wave * 2048;
        int base = 0;
        // C/D layout (16x16 shape): col = lane&15, row = quad*4 + reg
#pragma unroll
        for (int mi = 0; mi < 4; mi++) {
#pragma unroll
            for (int ni = 0; ni < 4; ni++) {
#pragma unroll
                for (int r = 0; r < 4; r++) {
                    int il = wrg * 64 + mi * 16 + quad * 4 + r;  // 0..255
                    int jl = wcg * 64 + ni * 16 + l16;           // 0..127
                    bool msk = (acc[mi][ni][r] > SIM_THR_I) && (rowJ + jl > rowI + il);
                    unsigned long long bal = __ballot(msk);
                    if (msk) {
                        int pos = base + __popcll(bal & ((1ull << lane) - 1ull));
                        if (pos < 2048) wl[pos] = (unsigned short)((il << 7) | jl);
                    }
                    base += __popcll(bal);
                }
            }
        }
        if (base > 2048) base = 2048;   // safety clamp (expected ~64/wave)

        for (int t = lane; t < base; t += 64) {
            int e = wl[t];
            int i = rowI + (e >> 7), j = rowJ + (e & 127);
            const float4* Li4 = (const float4*)(Lm + i * E_SZ);
            const float4* Pj4 = (const float4*)(Pm + j * E_SZ);
            const float4* Lj4 = (const float4*)(Lm + j * E_SZ);
            const float4* Pi4 = (const float4*)(Pm + i * E_SZ);
            float d = 0.f, d2 = 0.f;
#pragma unroll
            for (int q = 0; q < 4; q++) {
                float4 a = Li4[q], bb = Pj4[q];
                d += a.x * bb.x + a.y * bb.y + a.z * bb.z + a.w * bb.w;
                float4 a2 = Lj4[q], b2 = Pi4[q];
                d2 += a2.x * b2.x + a2.y * b2.y + a2.z * b2.z + a2.w * b2.w;
            }
            fsum += (ne[j] - d) + (ne[i] - d2);
            lcnt += 2;
        }
    }

#pragma unroll
    for (int off = 32; off > 0; off >>= 1) {
        fsum += __shfl_down(fsum, off, 64);
        lcnt += __shfl_down(lcnt, off, 64);
    }
    if (lane == 0) { redf[wave] = fsum; redc[wave] = lcnt; }
    __syncthreads();
    if (tid == 0) {
        float sv = 0.f;
        unsigned int c = 0u;
#pragma unroll
        for (int w = 0; w < 8; w++) { sv += redf[w]; c += redc[w]; }
        if (c > 0u) {
            atomicAdd(gsum, sv);
            atomicAdd(gcnt, c);
        }
        __threadfence();                       // make accumulators visible
        unsigned int old = atomicAdd(done, 1u);
        if (old == gridDim.x - 1) {            // last block finalizes
            float S = atomicAdd(gsum, 0.0f);   // device-scope atomic read
            unsigned int C = atomicAdd(gcnt, 0u);
            out[0] = (C > 0u) ? (S / (float)C) : 0.f;   // WEIGHT = 1.0
        }
    }
}

// ---------------------------------------------------------------------------
extern "C" void kernel_launch(void* const* d_in, const int* in_sizes, int n_in,
                              void* d_out, int out_size, void* d_ws, size_t ws_size,
                              hipStream_t stream) {
    const float* rp  = (const float*)d_in[0];
    const float* emb = (const float*)d_in[1];
    float* out = (float*)d_out;

    char* ws = (char*)d_ws;
    float*         gsum = (float*)(ws + 0);
    unsigned int*  gcnt = (unsigned int*)(ws + 4);
    unsigned int*  done = (unsigned int*)(ws + 8);
    float*         ne   = (float*)(ws + OFF_NE);
    float*         Lm   = (float*)(ws + OFF_L);
    float*         Pm   = (float*)(ws + OFF_P);
    unsigned char* embL = (unsigned char*)(ws + OFF_EMB);

    prep_kernel<<<512 + 32, 256, 0, stream>>>(rp, emb, embL, Lm, Pm, ne, gsum, gcnt, done);
    sim_kl_kernel<<<8 * GRID_PER_XCD, 512, 0, stream>>>(embL, Lm, Pm, ne, gsum, gcnt, done, out);
}

// Round 10
// 147.803 us; speedup vs baseline: 1.6912x; 1.1204x over previous
//
#include <hip/hip_runtime.h>
#include <hip/hip_bf16.h>
#include <math.h>

// Problem constants: B=8192, E=16, H=1024
#define B_SZ 8192
#define H_SZ 1024
#define E_SZ 16
#define SIM_THR_I 12903   // 0.8 * 127 * 127 = 12903.2 -> D > 12903
typedef float floatx4 __attribute__((ext_vector_type(4)));
typedef int   intx4   __attribute__((ext_vector_type(4)));

// ---------------- workspace layout ----------------
// 0: float gsum | 4: uint gcnt | 8: uint done
#define OFF_NE   4096
#define OFF_L    65536
#define OFF_P    (65536 + 524288)
#define OFF_EMB  2097152   // i8 emb, MFMA-native layout: 8 MB

// MFMA-native i8 layout (for mfma_i32_16x16x64_i8, lane q*16+m holds rows m,
// k in [q*16, q*16+16) contiguous):
// addr(r,k) = (r>>4)*16384 + (k>>6)*1024 + ((k>>4)&3)*256 + (r&15)*16 + (k&15)
// => one b128 read per fragment at group_base + round*1024 + lane*16.

__device__ __forceinline__ void gload16(const void* g, void* l) {
    __builtin_amdgcn_global_load_lds(
        (const __attribute__((address_space(1))) void*)g,
        (__attribute__((address_space(3))) void*)l, 16, 0, 0);
}

__device__ __forceinline__ unsigned int pack4_i8(float4 v, float s) {
    int a = (int)rintf(v.x * s), b = (int)rintf(v.y * s);
    int c = (int)rintf(v.z * s), d = (int)rintf(v.w * s);
    return (a & 255) | ((b & 255) << 8) | ((c & 255) << 16) | ((d & 255) << 24);
}

// ---------------------------------------------------------------------------
// Prep: blocks 0..511 normalize 16 rows each -> i8 MFMA-native layout with
// LDS-staged coalesced writes; blocks 512..543 softmax tables + accum init.
// ---------------------------------------------------------------------------
__global__ __launch_bounds__(256)
void prep_kernel(const float* __restrict__ rp,
                 const float* __restrict__ emb,
                 unsigned char* __restrict__ out8,
                 float* __restrict__ L, float* __restrict__ P,
                 float* __restrict__ ne,
                 float* __restrict__ gsum, unsigned int* __restrict__ gcnt,
                 unsigned int* __restrict__ done) {
    const int b = blockIdx.x;
    const int tid = threadIdx.x;
    if (b < 512) {
        __shared__ __align__(16) unsigned char stage[16 * 1040]; // padded rows
        const int wave = tid >> 6, lane = tid & 63;
        const int g = b;
#pragma unroll
        for (int t = 0; t < 4; t++) {
            int r = g * 16 + wave * 4 + t;
            const float4* row4 = (const float4*)(emb + (size_t)r * H_SZ);
            float4 v0 = row4[lane * 4 + 0], v1 = row4[lane * 4 + 1];
            float4 v2 = row4[lane * 4 + 2], v3 = row4[lane * 4 + 3];
            float ss = v0.x*v0.x + v0.y*v0.y + v0.z*v0.z + v0.w*v0.w
                     + v1.x*v1.x + v1.y*v1.y + v1.z*v1.z + v1.w*v1.w
                     + v2.x*v2.x + v2.y*v2.y + v2.z*v2.z + v2.w*v2.w
                     + v3.x*v3.x + v3.y*v3.y + v3.z*v3.z + v3.w*v3.w;
#pragma unroll
            for (int off = 32; off > 0; off >>= 1) ss += __shfl_down(ss, off, 64);
            ss = __shfl(ss, 0, 64);
            float s = rsqrtf(ss) * 127.0f;
            uint4 c;
            c.x = pack4_i8(v0, s);
            c.y = pack4_i8(v1, s);
            c.z = pack4_i8(v2, s);
            c.w = pack4_i8(v3, s);
            *(uint4*)(stage + (r & 15) * 1040 + lane * 16) = c;
        }
        __syncthreads();
        // coalesced write-out: dst chunk d -> row m = d&15, src chunk
        // c = (d>>6)*4 + ((d>>4)&3)
#pragma unroll
        for (int p = 0; p < 4; p++) {
            int d = p * 256 + tid;
            int m = d & 15;
            int c = (d >> 6) * 4 + ((d >> 4) & 3);
            uint4 v = *(const uint4*)(stage + m * 1040 + c * 16);
            *(uint4*)(out8 + (size_t)g * 16384 + (size_t)d * 16) = v;
        }
    } else {
        int i = (b - 512) * 256 + tid;
        if (i == 0) { *gsum = 0.f; *gcnt = 0u; *done = 0u; }
        if (i >= B_SZ) return;
        const float* x = rp + i * E_SZ;
        float v[E_SZ];
        float m = -INFINITY;
#pragma unroll
        for (int k = 0; k < E_SZ; k++) { v[k] = x[k]; m = fmaxf(m, v[k]); }
        float s = 0.f;
#pragma unroll
        for (int k = 0; k < E_SZ; k++) s += expf(v[k] - m);
        float lse = m + logf(s);
        float nent = 0.f;
#pragma unroll
        for (int k = 0; k < E_SZ; k++) {
            float l = v[k] - lse;
            float p = expf(l);
            L[i * E_SZ + k] = l;
            P[i * E_SZ + k] = p;
            nent += p * l;
        }
        ne[i] = nent;
    }
}

// ---------------------------------------------------------------------------
// Main: 256x256 i8 MFMA sim tiles (1024 threads, 16 waves, each a 64x64
// quadrant). 16 K-rounds of K=64; staging 2 gload16/wave/round (each wave
// stages its own 1-KB A-group and B-group); LDS double-buffer, one barrier
// per round. Phase-staggered round order across blocks to decorrelate
// same-address L2 traffic. 528 tiles = 66 per XCD (owner-computes classes
// {x, x+8, 23-x, 31-x}). Strict j>i pair rule; per-wave compaction; fused
// finalize via device-scope done counter.
// ---------------------------------------------------------------------------
__global__ __launch_bounds__(1024, 2)
void sim_kl_kernel(const unsigned char* __restrict__ embL,
                   const float* __restrict__ Lm, const float* __restrict__ Pm,
                   const float* __restrict__ ne,
                   float* __restrict__ gsum, unsigned int* __restrict__ gcnt,
                   unsigned int* __restrict__ done, float* __restrict__ out) {
    // smem[0..1]=A dbuf (16 KB each), smem[2..3]=B dbuf; epilogue overlays
    // the whole 64 KB as 16 x 2048-entry u16 lists.
    __shared__ __align__(16) char smem[4][16384];
    __shared__ float redf[16];
    __shared__ unsigned int redc[16];

    // --- blockIdx -> (bi, bj): XCD x owns bj panels {x, x+8, 23-x, 31-x} ---
    const int x = blockIdx.x & 7;
    int s = blockIdx.x >> 3;            // 0..65
    const int phase = s & 15;           // K-round stagger
    int bjs[4] = { x, x + 8, 23 - x, 31 - x };
    int bi = 0, bj = 0;
#pragma unroll
    for (int t = 0; t < 4; t++) {
        int n = bjs[t] + 1;             // tiles with bi <= bj
        if (s < n) { bj = bjs[t]; bi = s; break; }
        s -= n;
    }
    const int rowI = bi * 256, rowJ = bj * 256;

    const int tid  = threadIdx.x;
    const int lane = tid & 63;
    const int wave = tid >> 6;
    const int wrg = wave >> 2;          // A row quadrant 0..3 (x64 rows)
    const int wcg = wave & 3;           // B col quadrant 0..3 (x64 cols)
    const int quad = lane >> 4;
    const int l16  = lane & 15;

    intx4 acc[4][4];
#pragma unroll
    for (int mi = 0; mi < 4; mi++)
#pragma unroll
        for (int ni = 0; ni < 4; ni++) {
            intx4 z = {0, 0, 0, 0};
            acc[mi][ni] = z;
        }

    // staging: wave w stages A group w and B group w (1 KB each per round)
    const char* srcA = (const char*)embL + (size_t)(bi * 16 + wave) * 16384 + lane * 16;
    const char* srcB = (const char*)embL + (size_t)(bj * 16 + wave) * 16384 + lane * 16;
    const int gW = wave * 1024;         // wave-uniform LDS group offset

    {   // prologue: stage round 'phase' into buffer 0
        const int ko = phase * 1024;
        gload16(srcA + ko, smem[0] + gW);
        gload16(srcB + ko, smem[2] + gW);
    }

    const int aoff = wrg * 4096 + lane * 16;   // + mi*1024
    const int boff = wcg * 4096 + lane * 16;   // + ni*1024

    for (int kt = 0; kt < 16; kt++) {
        const int b = kt & 1;
        __syncthreads();                 // vmcnt drain + barrier: buffer b ready
        if (kt + 1 < 16) {               // prefetch next (staggered) round
            const int ko = (((kt + 1) + phase) & 15) * 1024;
            gload16(srcA + ko, smem[b ^ 1] + gW);
            gload16(srcB + ko, smem[2 + (b ^ 1)] + gW);
        }

        intx4 af[4], bf[4];
#pragma unroll
        for (int mi = 0; mi < 4; mi++)
            af[mi] = *(const intx4*)(smem[b] + aoff + mi * 1024);
#pragma unroll
        for (int ni = 0; ni < 4; ni++)
            bf[ni] = *(const intx4*)(smem[2 + b] + boff + ni * 1024);
#pragma unroll
        for (int mi = 0; mi < 4; mi++)
#pragma unroll
            for (int ni = 0; ni < 4; ni++)
                acc[mi][ni] = __builtin_amdgcn_mfma_i32_16x16x64_i8(
                    af[mi], bf[ni], acc[mi][ni], 0, 0, 0);
    }

    // ============== per-wave compaction epilogue (strict j>i) ===============
    __syncthreads();             // all tile reads done: overlay lists on smem
    unsigned short* wl = (unsigned short*)smem + wave * 2048;
    int base = 0;
    // C/D layout (16x16 shape): col = lane&15, row = quad*4 + reg
#pragma unroll
    for (int mi = 0; mi < 4; mi++) {
#pragma unroll
        for (int ni = 0; ni < 4; ni++) {
#pragma unroll
            for (int r = 0; r < 4; r++) {
                int il = wrg * 64 + mi * 16 + quad * 4 + r;  // 0..255
                int jl = wcg * 64 + ni * 16 + l16;           // 0..255
                bool msk = (acc[mi][ni][r] > SIM_THR_I) && (rowJ + jl > rowI + il);
                unsigned long long bal = __ballot(msk);
                if (msk) {
                    int pos = base + __popcll(bal & ((1ull << lane) - 1ull));
                    if (pos < 2048) wl[pos] = (unsigned short)((il << 8) | jl);
                }
                base += __popcll(bal);
            }
        }
    }
    if (base > 2048) base = 2048;   // safety clamp (expected ~32/wave)

    float fsum = 0.f;
    unsigned int lcnt = 0;
    for (int t = lane; t < base; t += 64) {
        int e = wl[t];
        int i = rowI + (e >> 8), j = rowJ + (e & 255);
        const float4* Li4 = (const float4*)(Lm + i * E_SZ);
        const float4* Pj4 = (const float4*)(Pm + j * E_SZ);
        const float4* Lj4 = (const float4*)(Lm + j * E_SZ);
        const float4* Pi4 = (const float4*)(Pm + i * E_SZ);
        float d = 0.f, d2 = 0.f;
#pragma unroll
        for (int q = 0; q < 4; q++) {
            float4 a = Li4[q], bb = Pj4[q];
            d += a.x * bb.x + a.y * bb.y + a.z * bb.z + a.w * bb.w;
            float4 a2 = Lj4[q], b2 = Pi4[q];
            d2 += a2.x * b2.x + a2.y * b2.y + a2.z * b2.z + a2.w * b2.w;
        }
        fsum += (ne[j] - d) + (ne[i] - d2);
        lcnt += 2;
    }

#pragma unroll
    for (int off = 32; off > 0; off >>= 1) {
        fsum += __shfl_down(fsum, off, 64);
        lcnt += __shfl_down(lcnt, off, 64);
    }
    if (lane == 0) { redf[wave] = fsum; redc[wave] = lcnt; }
    __syncthreads();
    if (tid == 0) {
        float sv = 0.f;
        unsigned int c = 0u;
#pragma unroll
        for (int w = 0; w < 16; w++) { sv += redf[w]; c += redc[w]; }
        if (c > 0u) {
            atomicAdd(gsum, sv);
            atomicAdd(gcnt, c);
        }
        __threadfence();                       // make accumulators visible
        unsigned int old = atomicAdd(done, 1u);
        if (old == gridDim.x - 1) {            // last block finalizes
            float S = atomicAdd(gsum, 0.0f);   // device-scope atomic read
            unsigned int C = atomicAdd(gcnt, 0u);
            out[0] = (C > 0u) ? (S / (float)C) : 0.f;   // WEIGHT = 1.0
        }
    }
}

// ---------------------------------------------------------------------------
extern "C" void kernel_launch(void* const* d_in, const int* in_sizes, int n_in,
                              void* d_out, int out_size, void* d_ws, size_t ws_size,
                              hipStream_t stream) {
    const float* rp  = (const float*)d_in[0];
    const float* emb = (const float*)d_in[1];
    float* out = (float*)d_out;

    char* ws = (char*)d_ws;
    float*         gsum = (float*)(ws + 0);
    unsigned int*  gcnt = (unsigned int*)(ws + 4);
    unsigned int*  done = (unsigned int*)(ws + 8);
    float*         ne   = (float*)(ws + OFF_NE);
    float*         Lm   = (float*)(ws + OFF_L);
    float*         Pm   = (float*)(ws + OFF_P);
    unsigned char* embL = (unsigned char*)(ws + OFF_EMB);

    prep_kernel<<<512 + 32, 256, 0, stream>>>(rp, emb, embL, Lm, Pm, ne, gsum, gcnt, done);
    sim_kl_kernel<<<528, 1024, 0, stream>>>(embL, Lm, Pm, ne, gsum, gcnt, done, out);
}